// Round 6
// baseline (513.234 us; speedup 1.0000x reference)
//
#include <hip/hip_runtime.h>
#include <hip/hip_bf16.h>

// Problem constants
#define DIMD   1024
#define BATCH  4
#define SEQ    4096
#define NTOK   (BATCH * SEQ)   // 16384
#define CHUNK  64              // recurrence chunk length
#define NCHUNK (SEQ / CHUNK)   // 64

// Fused kvr GEMM tiling: 512 threads, 8 waves as 4(M) x 2(N)
#define BMF 256
#define BNF 64
// Final GEMM tiling (m97 structure)
#define BM 128
#define BN 128
#define BK 32

typedef unsigned short ushort_t;
typedef __attribute__((ext_vector_type(8))) __bf16   bf16x8;
typedef __attribute__((ext_vector_type(4))) float    f32x4;
typedef __attribute__((ext_vector_type(8))) ushort_t u16x8;

__device__ __forceinline__ float b2f(ushort_t u) {
    union { unsigned int i; float f; } x;
    x.i = ((unsigned int)u) << 16;
    return x.f;
}

__device__ __forceinline__ ushort_t f2b(float f) {
    union { float f; unsigned int i; } x;
    x.f = f;
    unsigned int r = x.i + 0x7fffu + ((x.i >> 16) & 1u);  // RNE
    return (ushort_t)(r >> 16);
}

// ---------------------------------------------------------------------------
// Single conversion kernel: x (16M elems) then Wk,Wv,Wr,Wo (1M each) to bf16.
// One u16x8 unit (8 elems) per thread.
// ---------------------------------------------------------------------------
#define XU (NTOK * DIMD / 8)          // 2097152 units
#define WU (DIMD * DIMD / 8)          // 131072 units per weight matrix
__global__ __launch_bounds__(256)
void conv_all(const float* __restrict__ x,
              const float* __restrict__ W0, const float* __restrict__ W1,
              const float* __restrict__ W2, const float* __restrict__ W3,
              ushort_t* __restrict__ xb, ushort_t* __restrict__ Wb)
{
    const int i = blockIdx.x * 256 + threadIdx.x;   // 0 .. XU+4*WU-1
    const float* src;
    ushort_t* dst;
    int u;
    if (i < XU) {
        src = x; dst = xb; u = i;
    } else {
        const int wi = i - XU;
        const int m = wi >> 17;                     // WU = 2^17
        u = wi & (WU - 1);
        src = (m == 0) ? W0 : (m == 1) ? W1 : (m == 2) ? W2 : W3;
        dst = Wb + (size_t)m * DIMD * DIMD;
    }
    const float4* s4 = (const float4*)src;
    const float4 a = s4[(size_t)u * 2];
    const float4 b = s4[(size_t)u * 2 + 1];
    u16x8 o;
    o[0] = f2b(a.x); o[1] = f2b(a.y); o[2] = f2b(a.z); o[3] = f2b(a.w);
    o[4] = f2b(b.x); o[5] = f2b(b.y); o[6] = f2b(b.z); o[7] = f2b(b.w);
    *(u16x8*)(dst + (size_t)u * 8) = o;
}

// ---------------------------------------------------------------------------
// Fused 3-projection GEMM, BMF=256 x BNF=64, 512 threads (8 waves = 4M x 2N).
// Per-wave: 4x2 frags x 3 matrices (same regs as round-5), but staged
// cache-bytes drop 30% (A 512MB + B 384MB vs 1.28GB).
// Outputs kv = k*v (bf16), r = sigmoid (bf16), per-chunk weighted sums cs.
// Block rows = 4 whole 64-token chunks; wave-row wr owns chunk wr.
// ---------------------------------------------------------------------------
__global__ __launch_bounds__(512, 4)
void gemm_kvr(const ushort_t* __restrict__ A,
              const ushort_t* __restrict__ Wk,
              const ushort_t* __restrict__ Wv,
              const ushort_t* __restrict__ Wr,
              const float* __restrict__ td,
              ushort_t* __restrict__ Okv,
              ushort_t* __restrict__ Or,
              float* __restrict__ cs)
{
    __shared__ __align__(16) ushort_t As[BMF * BK];  // 16 KB
    __shared__ __align__(16) ushort_t Bk[BNF * BK];  // 4 KB
    __shared__ __align__(16) ushort_t Bv[BNF * BK];  // 4 KB
    __shared__ __align__(16) ushort_t Br[BNF * BK];  // 4 KB

    const int tid  = threadIdx.x;
    const int lane = tid & 63;
    const int wv   = tid >> 6;        // wave 0..7
    const int wr   = wv & 3;          // M quadrant (64 rows each)
    const int wc   = wv >> 2;         // N half (32 cols each)
    const int lrow = lane & 15;
    const int kq   = lane >> 4;

    const int row0 = blockIdx.x * BMF;
    const int e0   = blockIdx.y * BNF;

    f32x4 ak[4][2], av[4][2], ar[4][2];
#pragma unroll
    for (int i = 0; i < 4; i++)
#pragma unroll
        for (int j = 0; j < 2; j++) {
            ak[i][j] = f32x4{0.f, 0.f, 0.f, 0.f};
            av[i][j] = f32x4{0.f, 0.f, 0.f, 0.f};
            ar[i][j] = f32x4{0.f, 0.f, 0.f, 0.f};
        }

    for (int kt = 0; kt < DIMD / BK; ++kt) {
        const int k0 = kt * BK;

        __syncthreads();

        // A: 1024 x 16B chunks, 2 per thread. Wave-uniform base + lane*16.
#pragma unroll
        for (int it = 0; it < 2; ++it) {
            const int chunk = tid + it * 512;
            const int r = chunk >> 2;                  // 0..255
            const int c = (chunk & 3) << 3;
            const ushort_t* ga = A + (size_t)(row0 + r) * DIMD + k0 + c;
            __builtin_amdgcn_global_load_lds(
                (__attribute__((address_space(1))) void*)ga,
                (__attribute__((address_space(3))) void*)((char*)As + chunk * 16),
                16, 0, 0);
        }
        // B tiles: 256 chunks each. Waves 0-3: Bk+Br; waves 4-7: Bv.
        if (tid < 256) {
            const int r = tid >> 2;                    // 0..63
            const int c = (tid & 3) << 3;
            const size_t go = (size_t)(e0 + r) * DIMD + k0 + c;
            __builtin_amdgcn_global_load_lds(
                (__attribute__((address_space(1))) void*)(Wk + go),
                (__attribute__((address_space(3))) void*)((char*)Bk + tid * 16),
                16, 0, 0);
            __builtin_amdgcn_global_load_lds(
                (__attribute__((address_space(1))) void*)(Wr + go),
                (__attribute__((address_space(3))) void*)((char*)Br + tid * 16),
                16, 0, 0);
        } else {
            const int t2 = tid - 256;
            const int r = t2 >> 2;
            const int c = (t2 & 3) << 3;
            const size_t go = (size_t)(e0 + r) * DIMD + k0 + c;
            __builtin_amdgcn_global_load_lds(
                (__attribute__((address_space(1))) void*)(Wv + go),
                (__attribute__((address_space(3))) void*)((char*)Bv + t2 * 16),
                16, 0, 0);
        }

        __syncthreads();

        bf16x8 af[4], bk4[2], bv4[2], br4[2];
#pragma unroll
        for (int i = 0; i < 4; i++)
            af[i] = *(const bf16x8*)(As + (wr * 64 + i * 16 + lrow) * BK + kq * 8);
#pragma unroll
        for (int j = 0; j < 2; j++) {
            const int bo = (wc * 32 + j * 16 + lrow) * BK + kq * 8;
            bk4[j] = *(const bf16x8*)(Bk + bo);
            bv4[j] = *(const bf16x8*)(Bv + bo);
            br4[j] = *(const bf16x8*)(Br + bo);
        }

#pragma unroll
        for (int i = 0; i < 4; i++)
#pragma unroll
            for (int j = 0; j < 2; j++) {
                ak[i][j] = __builtin_amdgcn_mfma_f32_16x16x32_bf16(
                    af[i], bk4[j], ak[i][j], 0, 0, 0);
                av[i][j] = __builtin_amdgcn_mfma_f32_16x16x32_bf16(
                    af[i], bv4[j], av[i][j], 0, 0, 0);
                ar[i][j] = __builtin_amdgcn_mfma_f32_16x16x32_bf16(
                    af[i], br4[j], ar[i][j], 0, 0, 0);
            }
    }

    // Epilogue 1: kv & r. C/D layout: col = lane&15, row = quad*4 + reg.
#pragma unroll
    for (int i = 0; i < 4; i++)
#pragma unroll
        for (int j = 0; j < 2; j++)
#pragma unroll
            for (int r = 0; r < 4; r++) {
                const int row = row0 + wr * 64 + i * 16 + kq * 4 + r;
                const int col = e0 + wc * 32 + j * 16 + lrow;
                const size_t o = (size_t)row * DIMD + col;
                Okv[o] = f2b(ak[i][j][r] * av[i][j][r]);
                Or[o]  = f2b(1.f / (1.f + __expf(-ar[i][j][r])));
            }

    // Epilogue 2: per-chunk weighted sum  s(d) = sum_row decay^(63-row) k*v.
    // Wave wr owns chunk blockIdx.x*4 + wr; reduce kq quads via shfl_xor.
#pragma unroll
    for (int j = 0; j < 2; j++) {
        const int col = e0 + wc * 32 + j * 16 + lrow;
        const float w = -__expf(td[col]);
        float s = 0.f;
#pragma unroll
        for (int i = 0; i < 4; i++)
#pragma unroll
            for (int r = 0; r < 4; r++) {
                const int rl = i * 16 + kq * 4 + r;           // 0..63
                s += __expf(w * (float)(63 - rl)) * ak[i][j][r] * av[i][j][r];
            }
        s += __shfl_xor(s, 16);
        s += __shfl_xor(s, 32);
        if (kq == 0) {
            const int gchunk = blockIdx.x * 4 + wr;           // global chunk id
            cs[(size_t)gchunk * DIMD + col] = s;
        }
    }
}

// ---------------------------------------------------------------------------
// Final GEMM: C[n,e] = sum_d A[n,d] * W[e,d], f32 out. (m97 structure)
// ---------------------------------------------------------------------------
__global__ __launch_bounds__(256, 2)
void gemm_bt(const ushort_t* __restrict__ A,
             const ushort_t* __restrict__ W,
             float* __restrict__ Of)
{
    __shared__ __align__(16) ushort_t As[BM * BK];
    __shared__ __align__(16) ushort_t Bs[BN * BK];

    const int tid  = threadIdx.x;
    const int lane = tid & 63;
    const int wv   = tid >> 6;
    const int wr   = wv >> 1;
    const int wc   = wv & 1;
    const int lrow = lane & 15;
    const int kq   = lane >> 4;

    const int row0 = blockIdx.x * BM;
    const int e0   = blockIdx.y * BN;

    f32x4 acc[4][4];
#pragma unroll
    for (int i = 0; i < 4; i++)
#pragma unroll
        for (int j = 0; j < 4; j++)
            acc[i][j] = f32x4{0.f, 0.f, 0.f, 0.f};

    for (int kt = 0; kt < DIMD / BK; ++kt) {
        const int k0 = kt * BK;

        __syncthreads();

#pragma unroll
        for (int it = 0; it < 2; ++it) {
            const int chunk = tid + it * 256;
            const int r = chunk >> 2;
            const int c = (chunk & 3) << 3;
            const ushort_t* ga = A + (size_t)(row0 + r) * DIMD + k0 + c;
            const ushort_t* gb = W + (size_t)(e0 + r) * DIMD + k0 + c;
            __builtin_amdgcn_global_load_lds(
                (__attribute__((address_space(1))) void*)ga,
                (__attribute__((address_space(3))) void*)((char*)As + chunk * 16),
                16, 0, 0);
            __builtin_amdgcn_global_load_lds(
                (__attribute__((address_space(1))) void*)gb,
                (__attribute__((address_space(3))) void*)((char*)Bs + chunk * 16),
                16, 0, 0);
        }

        __syncthreads();

        bf16x8 af[4], bfr[4];
#pragma unroll
        for (int i = 0; i < 4; i++)
            af[i] = *(const bf16x8*)(As + (wr * 64 + i * 16 + lrow) * BK + kq * 8);
#pragma unroll
        for (int j = 0; j < 4; j++)
            bfr[j] = *(const bf16x8*)(Bs + (wc * 64 + j * 16 + lrow) * BK + kq * 8);

#pragma unroll
        for (int i = 0; i < 4; i++)
#pragma unroll
            for (int j = 0; j < 4; j++)
                acc[i][j] = __builtin_amdgcn_mfma_f32_16x16x32_bf16(
                    af[i], bfr[j], acc[i][j], 0, 0, 0);
    }

#pragma unroll
    for (int i = 0; i < 4; i++)
#pragma unroll
        for (int j = 0; j < 4; j++)
#pragma unroll
            for (int r = 0; r < 4; r++) {
                const int row = row0 + wr * 64 + i * 16 + kq * 4 + r;
                const int col = e0 + wc * 64 + j * 16 + lrow;
                Of[(size_t)row * DIMD + col] = acc[i][j][r];
            }
}

// ---------------------------------------------------------------------------
// Emit with fused chunk scan: incoming state st = prefix over raw chunk sums
// (cs is L2-resident, 1 MB), then out_pre = r*(st + eu*kv); st = decay*st+kv.
// 8 d's/thread; loop count c is wave-uniform (wave spans d only).
// ---------------------------------------------------------------------------
__global__ __launch_bounds__(256)
void emit(const ushort_t* __restrict__ kvb, const ushort_t* __restrict__ rb,
          const float* __restrict__ td, const float* __restrict__ tf,
          const float* __restrict__ cs, ushort_t* __restrict__ op)
{
    const int t  = blockIdx.x * 256 + threadIdx.x;   // 32768 threads
    const int d0 = (t & (DIMD / 8 - 1)) * 8;
    const int bc = t >> 7;
    const int c  = bc & (NCHUNK - 1);
    const int b  = bc >> 6;

    float w[8], decay[8], decayL[8], eu[8], st[8];
#pragma unroll
    for (int j = 0; j < 8; j++) {
        w[j]      = -__expf(td[d0 + j]);
        decay[j]  = __expf(w[j]);
        decayL[j] = __expf(w[j] * (float)CHUNK);
        eu[j]     = __expf(tf[d0 + j]);
        st[j]     = 0.f;
    }

    // Inline scan: st = sum_{c'<c} decayL^(c-1-c') * S[c']
    for (int cc = 0; cc < c; ++cc) {
        const float* sp = cs + (((size_t)b * NCHUNK + cc) * DIMD + d0);
        const float4 s0 = *(const float4*)sp;
        const float4 s1 = *(const float4*)(sp + 4);
        st[0] = decayL[0] * st[0] + s0.x;  st[1] = decayL[1] * st[1] + s0.y;
        st[2] = decayL[2] * st[2] + s0.z;  st[3] = decayL[3] * st[3] + s0.w;
        st[4] = decayL[4] * st[4] + s1.x;  st[5] = decayL[5] * st[5] + s1.y;
        st[6] = decayL[6] * st[6] + s1.z;  st[7] = decayL[7] * st[7] + s1.w;
    }

    size_t off = ((size_t)b * SEQ + (size_t)c * CHUNK) * DIMD + d0;
#pragma unroll 8
    for (int i = 0; i < CHUNK; i++) {
        const u16x8 kv8 = *(const u16x8*)(kvb + off);
        const u16x8 r8  = *(const u16x8*)(rb + off);
        u16x8 o8;
#pragma unroll
        for (int j = 0; j < 8; j++) {
            const float kv = b2f(kv8[j]);
            o8[j] = f2b(b2f(r8[j]) * (st[j] + eu[j] * kv));
            st[j] = decay[j] * st[j] + kv;
        }
        *(u16x8*)(op + off) = o8;
        off += DIMD;
    }
}

// ---------------------------------------------------------------------------
// ws: xb/pbuf 32 MiB + weights 8 MiB + cs 1 MiB = 41 MiB.
// d_out (64 MiB f32) doubles as kvb+rb scratch (dead before final GEMM).
// ---------------------------------------------------------------------------
extern "C" void kernel_launch(void* const* d_in, const int* in_sizes, int n_in,
                              void* d_out, int out_size, void* d_ws, size_t ws_size,
                              hipStream_t stream)
{
    const float* x  = (const float*)d_in[0];
    const float* Wk = (const float*)d_in[1];
    const float* Wv = (const float*)d_in[2];
    const float* Wr = (const float*)d_in[3];
    const float* Wo = (const float*)d_in[4];
    const float* td = (const float*)d_in[5];
    const float* tf = (const float*)d_in[6];

    ushort_t* xb  = (ushort_t*)d_ws;                       // 32 MiB; reused as pbuf
    ushort_t* Wb  = xb + (size_t)NTOK * DIMD;              // 8 MiB (4 matrices)
    ushort_t* Wkb = Wb;
    ushort_t* Wvb = Wb + (size_t)DIMD * DIMD;
    ushort_t* Wrb = Wb + 2 * (size_t)DIMD * DIMD;
    ushort_t* Wob = Wb + 3 * (size_t)DIMD * DIMD;
    float*    cs  = (float*)(Wb + 4 * (size_t)DIMD * DIMD); // 1 MiB
    ushort_t* pbuf = xb;

    ushort_t* kvb = (ushort_t*)d_out;                      // 32 MiB scratch
    ushort_t* rb  = kvb + (size_t)NTOK * DIMD;             // 32 MiB scratch
    float*    out = (float*)d_out;

    // 0) all conversions in one dispatch
    conv_all<<<(XU + 4 * WU) / 256, 256, 0, stream>>>(x, Wk, Wv, Wr, Wo, xb, Wb);

    // 1) fused kv & r projections + per-chunk aggregates
    gemm_kvr<<<dim3(NTOK / BMF, DIMD / BNF), 512, 0, stream>>>(
        xb, Wkb, Wvb, Wrb, td, kvb, rb, cs);

    // 2) emit (with inline chunk-boundary scan) -> pbuf (xb region)
    emit<<<BATCH * NCHUNK * (DIMD / 8) / 256, 256, 0, stream>>>(
        kvb, rb, td, tf, cs, pbuf);

    // 3) out = out_pre @ Wo^T (f32 epilogue, overwrites d_out)
    gemm_bt<<<dim3(NTOK / BM, DIMD / BN), 256, 0, stream>>>(pbuf, Wob, out);
}

// Round 7
// 367.274 us; speedup vs baseline: 1.3974x; 1.3974x over previous
//
#include <hip/hip_runtime.h>
#include <hip/hip_bf16.h>

// Problem constants
#define DIMD   1024
#define BATCH  4
#define SEQ    4096
#define NTOK   (BATCH * SEQ)   // 16384
#define CHUNK  64              // recurrence chunk length
#define NCHUNK (SEQ / CHUNK)   // 64

// Fused kvr GEMM tiling: 512 threads, 8 waves as 4(M) x 2(N)
#define BMF 256
#define BNF 64
// Final GEMM tiling (m97 structure)
#define BM 128
#define BN 128
#define BK 32

typedef unsigned short ushort_t;
typedef __attribute__((ext_vector_type(8))) __bf16   bf16x8;
typedef __attribute__((ext_vector_type(4))) float    f32x4;
typedef __attribute__((ext_vector_type(8))) ushort_t u16x8;

__device__ __forceinline__ float b2f(ushort_t u) {
    union { unsigned int i; float f; } x;
    x.i = ((unsigned int)u) << 16;
    return x.f;
}

__device__ __forceinline__ ushort_t f2b(float f) {
    union { float f; unsigned int i; } x;
    x.f = f;
    unsigned int r = x.i + 0x7fffu + ((x.i >> 16) & 1u);  // RNE
    return (ushort_t)(r >> 16);
}

// ---------------------------------------------------------------------------
// Single conversion kernel: x (16M elems) then Wk,Wv,Wr,Wo (1M each) to bf16.
// One u16x8 unit (8 elems) per thread.
// ---------------------------------------------------------------------------
#define XU (NTOK * DIMD / 8)          // 2097152 units
#define WU (DIMD * DIMD / 8)          // 131072 units per weight matrix
__global__ __launch_bounds__(256)
void conv_all(const float* __restrict__ x,
              const float* __restrict__ W0, const float* __restrict__ W1,
              const float* __restrict__ W2, const float* __restrict__ W3,
              ushort_t* __restrict__ xb, ushort_t* __restrict__ Wb)
{
    const int i = blockIdx.x * 256 + threadIdx.x;   // 0 .. XU+4*WU-1
    const float* src;
    ushort_t* dst;
    int u;
    if (i < XU) {
        src = x; dst = xb; u = i;
    } else {
        const int wi = i - XU;
        const int m = wi >> 17;                     // WU = 2^17
        u = wi & (WU - 1);
        src = (m == 0) ? W0 : (m == 1) ? W1 : (m == 2) ? W2 : W3;
        dst = Wb + (size_t)m * DIMD * DIMD;
    }
    const float4* s4 = (const float4*)src;
    const float4 a = s4[(size_t)u * 2];
    const float4 b = s4[(size_t)u * 2 + 1];
    u16x8 o;
    o[0] = f2b(a.x); o[1] = f2b(a.y); o[2] = f2b(a.z); o[3] = f2b(a.w);
    o[4] = f2b(b.x); o[5] = f2b(b.y); o[6] = f2b(b.z); o[7] = f2b(b.w);
    *(u16x8*)(dst + (size_t)u * 8) = o;
}

// ---------------------------------------------------------------------------
// Fused 3-projection GEMM, BMF=256 x BNF=64, 512 threads (8 waves = 4M x 2N).
// launch_bounds (512, 2): 2 waves/EU -> 256-VGPR cap, same per-wave budget as
// the proven round-5 config. (512,4) capped at 128 and spilled: WRITE_SIZE
// 67->589 MB, MfmaUtil 36->14%. Do not raise the second arg.
// Staged cache-bytes: A 32MBx16 + B 6MBx64 = 896 MB (vs 1.28 GB at BMF=128).
// ---------------------------------------------------------------------------
__global__ __launch_bounds__(512, 2)
void gemm_kvr(const ushort_t* __restrict__ A,
              const ushort_t* __restrict__ Wk,
              const ushort_t* __restrict__ Wv,
              const ushort_t* __restrict__ Wr,
              const float* __restrict__ td,
              ushort_t* __restrict__ Okv,
              ushort_t* __restrict__ Or,
              float* __restrict__ cs)
{
    __shared__ __align__(16) ushort_t As[BMF * BK];  // 16 KB
    __shared__ __align__(16) ushort_t Bk[BNF * BK];  // 4 KB
    __shared__ __align__(16) ushort_t Bv[BNF * BK];  // 4 KB
    __shared__ __align__(16) ushort_t Br[BNF * BK];  // 4 KB

    const int tid  = threadIdx.x;
    const int lane = tid & 63;
    const int wv   = tid >> 6;        // wave 0..7
    const int wr   = wv & 3;          // M quadrant (64 rows each)
    const int wc   = wv >> 2;         // N half (32 cols each)
    const int lrow = lane & 15;
    const int kq   = lane >> 4;

    const int row0 = blockIdx.x * BMF;
    const int e0   = blockIdx.y * BNF;

    f32x4 ak[4][2], av[4][2], ar[4][2];
#pragma unroll
    for (int i = 0; i < 4; i++)
#pragma unroll
        for (int j = 0; j < 2; j++) {
            ak[i][j] = f32x4{0.f, 0.f, 0.f, 0.f};
            av[i][j] = f32x4{0.f, 0.f, 0.f, 0.f};
            ar[i][j] = f32x4{0.f, 0.f, 0.f, 0.f};
        }

    for (int kt = 0; kt < DIMD / BK; ++kt) {
        const int k0 = kt * BK;

        __syncthreads();

        // A: 1024 x 16B chunks, 2 per thread. Wave-uniform base + lane*16.
#pragma unroll
        for (int it = 0; it < 2; ++it) {
            const int chunk = tid + it * 512;
            const int r = chunk >> 2;                  // 0..255
            const int c = (chunk & 3) << 3;
            const ushort_t* ga = A + (size_t)(row0 + r) * DIMD + k0 + c;
            __builtin_amdgcn_global_load_lds(
                (__attribute__((address_space(1))) void*)ga,
                (__attribute__((address_space(3))) void*)((char*)As + chunk * 16),
                16, 0, 0);
        }
        // B tiles: 256 chunks each. Waves 0-3: Bk+Br; waves 4-7: Bv.
        if (tid < 256) {
            const int r = tid >> 2;                    // 0..63
            const int c = (tid & 3) << 3;
            const size_t go = (size_t)(e0 + r) * DIMD + k0 + c;
            __builtin_amdgcn_global_load_lds(
                (__attribute__((address_space(1))) void*)(Wk + go),
                (__attribute__((address_space(3))) void*)((char*)Bk + tid * 16),
                16, 0, 0);
            __builtin_amdgcn_global_load_lds(
                (__attribute__((address_space(1))) void*)(Wr + go),
                (__attribute__((address_space(3))) void*)((char*)Br + tid * 16),
                16, 0, 0);
        } else {
            const int t2 = tid - 256;
            const int r = t2 >> 2;
            const int c = (t2 & 3) << 3;
            const size_t go = (size_t)(e0 + r) * DIMD + k0 + c;
            __builtin_amdgcn_global_load_lds(
                (__attribute__((address_space(1))) void*)(Wv + go),
                (__attribute__((address_space(3))) void*)((char*)Bv + t2 * 16),
                16, 0, 0);
        }

        __syncthreads();

        bf16x8 af[4], bk4[2], bv4[2], br4[2];
#pragma unroll
        for (int i = 0; i < 4; i++)
            af[i] = *(const bf16x8*)(As + (wr * 64 + i * 16 + lrow) * BK + kq * 8);
#pragma unroll
        for (int j = 0; j < 2; j++) {
            const int bo = (wc * 32 + j * 16 + lrow) * BK + kq * 8;
            bk4[j] = *(const bf16x8*)(Bk + bo);
            bv4[j] = *(const bf16x8*)(Bv + bo);
            br4[j] = *(const bf16x8*)(Br + bo);
        }

#pragma unroll
        for (int i = 0; i < 4; i++)
#pragma unroll
            for (int j = 0; j < 2; j++) {
                ak[i][j] = __builtin_amdgcn_mfma_f32_16x16x32_bf16(
                    af[i], bk4[j], ak[i][j], 0, 0, 0);
                av[i][j] = __builtin_amdgcn_mfma_f32_16x16x32_bf16(
                    af[i], bv4[j], av[i][j], 0, 0, 0);
                ar[i][j] = __builtin_amdgcn_mfma_f32_16x16x32_bf16(
                    af[i], br4[j], ar[i][j], 0, 0, 0);
            }
    }

    // Epilogue 1: kv & r. C/D layout: col = lane&15, row = quad*4 + reg.
#pragma unroll
    for (int i = 0; i < 4; i++)
#pragma unroll
        for (int j = 0; j < 2; j++)
#pragma unroll
            for (int r = 0; r < 4; r++) {
                const int row = row0 + wr * 64 + i * 16 + kq * 4 + r;
                const int col = e0 + wc * 32 + j * 16 + lrow;
                const size_t o = (size_t)row * DIMD + col;
                Okv[o] = f2b(ak[i][j][r] * av[i][j][r]);
                Or[o]  = f2b(1.f / (1.f + __expf(-ar[i][j][r])));
            }

    // Epilogue 2: per-chunk weighted sum  s(d) = sum_row decay^(63-row) k*v.
    // Wave wr owns chunk blockIdx.x*4 + wr; reduce kq quads via shfl_xor.
#pragma unroll
    for (int j = 0; j < 2; j++) {
        const int col = e0 + wc * 32 + j * 16 + lrow;
        const float w = -__expf(td[col]);
        float s = 0.f;
#pragma unroll
        for (int i = 0; i < 4; i++)
#pragma unroll
            for (int r = 0; r < 4; r++) {
                const int rl = i * 16 + kq * 4 + r;           // 0..63
                s += __expf(w * (float)(63 - rl)) * ak[i][j][r] * av[i][j][r];
            }
        s += __shfl_xor(s, 16);
        s += __shfl_xor(s, 32);
        if (kq == 0) {
            const int gchunk = blockIdx.x * 4 + wr;           // global chunk id
            cs[(size_t)gchunk * DIMD + col] = s;
        }
    }
}

// ---------------------------------------------------------------------------
// Final GEMM: C[n,e] = sum_d A[n,d] * W[e,d], f32 out. (m97 structure)
// ---------------------------------------------------------------------------
__global__ __launch_bounds__(256, 2)
void gemm_bt(const ushort_t* __restrict__ A,
             const ushort_t* __restrict__ W,
             float* __restrict__ Of)
{
    __shared__ __align__(16) ushort_t As[BM * BK];
    __shared__ __align__(16) ushort_t Bs[BN * BK];

    const int tid  = threadIdx.x;
    const int lane = tid & 63;
    const int wv   = tid >> 6;
    const int wr   = wv >> 1;
    const int wc   = wv & 1;
    const int lrow = lane & 15;
    const int kq   = lane >> 4;

    const int row0 = blockIdx.x * BM;
    const int e0   = blockIdx.y * BN;

    f32x4 acc[4][4];
#pragma unroll
    for (int i = 0; i < 4; i++)
#pragma unroll
        for (int j = 0; j < 4; j++)
            acc[i][j] = f32x4{0.f, 0.f, 0.f, 0.f};

    for (int kt = 0; kt < DIMD / BK; ++kt) {
        const int k0 = kt * BK;

        __syncthreads();

#pragma unroll
        for (int it = 0; it < 2; ++it) {
            const int chunk = tid + it * 256;
            const int r = chunk >> 2;
            const int c = (chunk & 3) << 3;
            const ushort_t* ga = A + (size_t)(row0 + r) * DIMD + k0 + c;
            const ushort_t* gb = W + (size_t)(e0 + r) * DIMD + k0 + c;
            __builtin_amdgcn_global_load_lds(
                (__attribute__((address_space(1))) void*)ga,
                (__attribute__((address_space(3))) void*)((char*)As + chunk * 16),
                16, 0, 0);
            __builtin_amdgcn_global_load_lds(
                (__attribute__((address_space(1))) void*)gb,
                (__attribute__((address_space(3))) void*)((char*)Bs + chunk * 16),
                16, 0, 0);
        }

        __syncthreads();

        bf16x8 af[4], bfr[4];
#pragma unroll
        for (int i = 0; i < 4; i++)
            af[i] = *(const bf16x8*)(As + (wr * 64 + i * 16 + lrow) * BK + kq * 8);
#pragma unroll
        for (int j = 0; j < 4; j++)
            bfr[j] = *(const bf16x8*)(Bs + (wc * 64 + j * 16 + lrow) * BK + kq * 8);

#pragma unroll
        for (int i = 0; i < 4; i++)
#pragma unroll
            for (int j = 0; j < 4; j++)
                acc[i][j] = __builtin_amdgcn_mfma_f32_16x16x32_bf16(
                    af[i], bfr[j], acc[i][j], 0, 0, 0);
    }

#pragma unroll
    for (int i = 0; i < 4; i++)
#pragma unroll
        for (int j = 0; j < 4; j++)
#pragma unroll
            for (int r = 0; r < 4; r++) {
                const int row = row0 + wr * 64 + i * 16 + kq * 4 + r;
                const int col = e0 + wc * 64 + j * 16 + lrow;
                Of[(size_t)row * DIMD + col] = acc[i][j][r];
            }
}

// ---------------------------------------------------------------------------
// Emit with fused chunk scan: incoming state st = prefix over raw chunk sums
// (cs is L2-resident, 1 MB), then out_pre = r*(st + eu*kv); st = decay*st+kv.
// 8 d's/thread; loop count c is wave-uniform (wave spans d only).
// ---------------------------------------------------------------------------
__global__ __launch_bounds__(256)
void emit(const ushort_t* __restrict__ kvb, const ushort_t* __restrict__ rb,
          const float* __restrict__ td, const float* __restrict__ tf,
          const float* __restrict__ cs, ushort_t* __restrict__ op)
{
    const int t  = blockIdx.x * 256 + threadIdx.x;   // 32768 threads
    const int d0 = (t & (DIMD / 8 - 1)) * 8;
    const int bc = t >> 7;
    const int c  = bc & (NCHUNK - 1);
    const int b  = bc >> 6;

    float w[8], decay[8], decayL[8], eu[8], st[8];
#pragma unroll
    for (int j = 0; j < 8; j++) {
        w[j]      = -__expf(td[d0 + j]);
        decay[j]  = __expf(w[j]);
        decayL[j] = __expf(w[j] * (float)CHUNK);
        eu[j]     = __expf(tf[d0 + j]);
        st[j]     = 0.f;
    }

    // Inline scan: st = sum_{c'<c} decayL^(c-1-c') * S[c']
    for (int cc = 0; cc < c; ++cc) {
        const float* sp = cs + (((size_t)b * NCHUNK + cc) * DIMD + d0);
        const float4 s0 = *(const float4*)sp;
        const float4 s1 = *(const float4*)(sp + 4);
        st[0] = decayL[0] * st[0] + s0.x;  st[1] = decayL[1] * st[1] + s0.y;
        st[2] = decayL[2] * st[2] + s0.z;  st[3] = decayL[3] * st[3] + s0.w;
        st[4] = decayL[4] * st[4] + s1.x;  st[5] = decayL[5] * st[5] + s1.y;
        st[6] = decayL[6] * st[6] + s1.z;  st[7] = decayL[7] * st[7] + s1.w;
    }

    size_t off = ((size_t)b * SEQ + (size_t)c * CHUNK) * DIMD + d0;
#pragma unroll 8
    for (int i = 0; i < CHUNK; i++) {
        const u16x8 kv8 = *(const u16x8*)(kvb + off);
        const u16x8 r8  = *(const u16x8*)(rb + off);
        u16x8 o8;
#pragma unroll
        for (int j = 0; j < 8; j++) {
            const float kv = b2f(kv8[j]);
            o8[j] = f2b(b2f(r8[j]) * (st[j] + eu[j] * kv));
            st[j] = decay[j] * st[j] + kv;
        }
        *(u16x8*)(op + off) = o8;
        off += DIMD;
    }
}

// ---------------------------------------------------------------------------
// ws: xb/pbuf 32 MiB + weights 8 MiB + cs 1 MiB = 41 MiB.
// d_out (64 MiB f32) doubles as kvb+rb scratch (dead before final GEMM).
// ---------------------------------------------------------------------------
extern "C" void kernel_launch(void* const* d_in, const int* in_sizes, int n_in,
                              void* d_out, int out_size, void* d_ws, size_t ws_size,
                              hipStream_t stream)
{
    const float* x  = (const float*)d_in[0];
    const float* Wk = (const float*)d_in[1];
    const float* Wv = (const float*)d_in[2];
    const float* Wr = (const float*)d_in[3];
    const float* Wo = (const float*)d_in[4];
    const float* td = (const float*)d_in[5];
    const float* tf = (const float*)d_in[6];

    ushort_t* xb  = (ushort_t*)d_ws;                       // 32 MiB; reused as pbuf
    ushort_t* Wb  = xb + (size_t)NTOK * DIMD;              // 8 MiB (4 matrices)
    ushort_t* Wkb = Wb;
    ushort_t* Wvb = Wb + (size_t)DIMD * DIMD;
    ushort_t* Wrb = Wb + 2 * (size_t)DIMD * DIMD;
    ushort_t* Wob = Wb + 3 * (size_t)DIMD * DIMD;
    float*    cs  = (float*)(Wb + 4 * (size_t)DIMD * DIMD); // 1 MiB
    ushort_t* pbuf = xb;

    ushort_t* kvb = (ushort_t*)d_out;                      // 32 MiB scratch
    ushort_t* rb  = kvb + (size_t)NTOK * DIMD;             // 32 MiB scratch
    float*    out = (float*)d_out;

    // 0) all conversions in one dispatch
    conv_all<<<(XU + 4 * WU) / 256, 256, 0, stream>>>(x, Wk, Wv, Wr, Wo, xb, Wb);

    // 1) fused kv & r projections + per-chunk aggregates
    gemm_kvr<<<dim3(NTOK / BMF, DIMD / BNF), 512, 0, stream>>>(
        xb, Wkb, Wvb, Wrb, td, kvb, rb, cs);

    // 2) emit (with inline chunk-boundary scan) -> pbuf (xb region)
    emit<<<BATCH * NCHUNK * (DIMD / 8) / 256, 256, 0, stream>>>(
        kvb, rb, td, tf, cs, pbuf);

    // 3) out = out_pre @ Wo^T (f32 epilogue, overwrites d_out)
    gemm_bt<<<dim3(NTOK / BM, DIMD / BN), 256, 0, stream>>>(pbuf, Wob, out);
}

// Round 8
// 324.246 us; speedup vs baseline: 1.5829x; 1.1327x over previous
//
#include <hip/hip_runtime.h>
#include <hip/hip_bf16.h>

// Problem constants
#define DIMD   1024
#define BATCH  4
#define SEQ    4096
#define NTOK   (BATCH * SEQ)   // 16384
#define CHUNK  64              // recurrence chunk length
#define NCHUNK (SEQ / CHUNK)   // 64

// Fused kvr GEMM tiling (round-5 proven config): 256 threads, BM=128 x BNF=64
#define BMF 128
#define BNF 64
// Final GEMM tiling (m97 structure)
#define BM 128
#define BN 128
#define BK 32

typedef unsigned short ushort_t;
typedef __attribute__((ext_vector_type(8))) __bf16   bf16x8;
typedef __attribute__((ext_vector_type(4))) float    f32x4;
typedef __attribute__((ext_vector_type(8))) ushort_t u16x8;

__device__ __forceinline__ float b2f(ushort_t u) {
    union { unsigned int i; float f; } x;
    x.i = ((unsigned int)u) << 16;
    return x.f;
}

__device__ __forceinline__ ushort_t f2b(float f) {
    union { float f; unsigned int i; } x;
    x.f = f;
    unsigned int r = x.i + 0x7fffu + ((x.i >> 16) & 1u);  // RNE
    return (ushort_t)(r >> 16);
}

// ---------------------------------------------------------------------------
// Single conversion kernel: x (16M elems) then Wk,Wv,Wr,Wo (1M each) to bf16.
// One u16x8 unit (8 elems) per thread.
// ---------------------------------------------------------------------------
#define XU (NTOK * DIMD / 8)          // 2097152 units
#define WU (DIMD * DIMD / 8)          // 131072 units per weight matrix
__global__ __launch_bounds__(256)
void conv_all(const float* __restrict__ x,
              const float* __restrict__ W0, const float* __restrict__ W1,
              const float* __restrict__ W2, const float* __restrict__ W3,
              ushort_t* __restrict__ xb, ushort_t* __restrict__ Wb)
{
    const int i = blockIdx.x * 256 + threadIdx.x;   // 0 .. XU+4*WU-1
    const float* src;
    ushort_t* dst;
    int u;
    if (i < XU) {
        src = x; dst = xb; u = i;
    } else {
        const int wi = i - XU;
        const int m = wi >> 17;                     // WU = 2^17
        u = wi & (WU - 1);
        src = (m == 0) ? W0 : (m == 1) ? W1 : (m == 2) ? W2 : W3;
        dst = Wb + (size_t)m * DIMD * DIMD;
    }
    const float4* s4 = (const float4*)src;
    const float4 a = s4[(size_t)u * 2];
    const float4 b = s4[(size_t)u * 2 + 1];
    u16x8 o;
    o[0] = f2b(a.x); o[1] = f2b(a.y); o[2] = f2b(a.z); o[3] = f2b(a.w);
    o[4] = f2b(b.x); o[5] = f2b(b.y); o[6] = f2b(b.z); o[7] = f2b(b.w);
    *(u16x8*)(dst + (size_t)u * 8) = o;
}

// ---------------------------------------------------------------------------
// Fused 3-projection GEMM, BMF=128 x BNF=64, 256 threads (4 waves = 2M x 2N).
// ROUND-5 PROVEN CONFIG: VGPR 84, 2 blocks/CU, 123 us, MfmaUtil 36%.
// Do NOT grow the tile: BN=128 x3 mats = register cliff (r4); BM=256/512thr =
// 1 block/CU barrier exposure (r7); (512,4) = spill catastrophe (r6).
// Outputs kv = k*v (bf16), r = sigmoid (bf16), per-chunk weighted sums cs.
// Block rows = 2 whole 64-token chunks; wave-row wr owns chunk wr.
// ---------------------------------------------------------------------------
__global__ __launch_bounds__(256, 2)
void gemm_kvr(const ushort_t* __restrict__ A,
              const ushort_t* __restrict__ Wk,
              const ushort_t* __restrict__ Wv,
              const ushort_t* __restrict__ Wr,
              const float* __restrict__ td,
              ushort_t* __restrict__ Okv,
              ushort_t* __restrict__ Or,
              float* __restrict__ cs)
{
    __shared__ __align__(16) ushort_t As[BMF * BK];  // 8 KB
    __shared__ __align__(16) ushort_t Bk[BNF * BK];  // 4 KB
    __shared__ __align__(16) ushort_t Bv[BNF * BK];  // 4 KB
    __shared__ __align__(16) ushort_t Br[BNF * BK];  // 4 KB

    const int tid  = threadIdx.x;
    const int lane = tid & 63;
    const int wv   = tid >> 6;        // wave 0..3
    const int wr   = wv >> 1;         // row half (= chunk within block)
    const int wc   = wv & 1;          // col half (32 cols)
    const int lrow = lane & 15;
    const int kq   = lane >> 4;

    const int row0 = blockIdx.x * BMF;
    const int e0   = blockIdx.y * BNF;

    f32x4 ak[4][2], av[4][2], ar[4][2];
#pragma unroll
    for (int i = 0; i < 4; i++)
#pragma unroll
        for (int j = 0; j < 2; j++) {
            ak[i][j] = f32x4{0.f, 0.f, 0.f, 0.f};
            av[i][j] = f32x4{0.f, 0.f, 0.f, 0.f};
            ar[i][j] = f32x4{0.f, 0.f, 0.f, 0.f};
        }

    for (int kt = 0; kt < DIMD / BK; ++kt) {
        const int k0 = kt * BK;

        __syncthreads();

        // A: 512 x 16B chunks (2/thread); each B: 256 chunks (1/thread).
#pragma unroll
        for (int it = 0; it < 2; ++it) {
            const int chunk = tid + it * 256;
            const int r = chunk >> 2;
            const int c = (chunk & 3) << 3;
            const ushort_t* ga = A + (size_t)(row0 + r) * DIMD + k0 + c;
            __builtin_amdgcn_global_load_lds(
                (__attribute__((address_space(1))) void*)ga,
                (__attribute__((address_space(3))) void*)((char*)As + chunk * 16),
                16, 0, 0);
        }
        {
            const int r = tid >> 2;                 // 0..63
            const int c = (tid & 3) << 3;
            const size_t go = (size_t)(e0 + r) * DIMD + k0 + c;
            __builtin_amdgcn_global_load_lds(
                (__attribute__((address_space(1))) void*)(Wk + go),
                (__attribute__((address_space(3))) void*)((char*)Bk + tid * 16),
                16, 0, 0);
            __builtin_amdgcn_global_load_lds(
                (__attribute__((address_space(1))) void*)(Wv + go),
                (__attribute__((address_space(3))) void*)((char*)Bv + tid * 16),
                16, 0, 0);
            __builtin_amdgcn_global_load_lds(
                (__attribute__((address_space(1))) void*)(Wr + go),
                (__attribute__((address_space(3))) void*)((char*)Br + tid * 16),
                16, 0, 0);
        }

        __syncthreads();

        bf16x8 af[4], bk4[2], bv4[2], br4[2];
#pragma unroll
        for (int i = 0; i < 4; i++)
            af[i] = *(const bf16x8*)(As + (wr * 64 + i * 16 + lrow) * BK + kq * 8);
#pragma unroll
        for (int j = 0; j < 2; j++) {
            const int bo = (wc * 32 + j * 16 + lrow) * BK + kq * 8;
            bk4[j] = *(const bf16x8*)(Bk + bo);
            bv4[j] = *(const bf16x8*)(Bv + bo);
            br4[j] = *(const bf16x8*)(Br + bo);
        }

#pragma unroll
        for (int i = 0; i < 4; i++)
#pragma unroll
            for (int j = 0; j < 2; j++) {
                ak[i][j] = __builtin_amdgcn_mfma_f32_16x16x32_bf16(
                    af[i], bk4[j], ak[i][j], 0, 0, 0);
                av[i][j] = __builtin_amdgcn_mfma_f32_16x16x32_bf16(
                    af[i], bv4[j], av[i][j], 0, 0, 0);
                ar[i][j] = __builtin_amdgcn_mfma_f32_16x16x32_bf16(
                    af[i], br4[j], ar[i][j], 0, 0, 0);
            }
    }

    // Epilogue 1: kv & r. C/D layout: col = lane&15, row = quad*4 + reg.
#pragma unroll
    for (int i = 0; i < 4; i++)
#pragma unroll
        for (int j = 0; j < 2; j++)
#pragma unroll
            for (int r = 0; r < 4; r++) {
                const int row = row0 + wr * 64 + i * 16 + kq * 4 + r;
                const int col = e0 + wc * 32 + j * 16 + lrow;
                const size_t o = (size_t)row * DIMD + col;
                Okv[o] = f2b(ak[i][j][r] * av[i][j][r]);
                Or[o]  = f2b(1.f / (1.f + __expf(-ar[i][j][r])));
            }

    // Epilogue 2: per-chunk weighted sum  s(d) = sum_row decay^(63-row) k*v.
    // Wave wr owns chunk blockIdx.x*2 + wr; reduce kq quads via shfl_xor.
#pragma unroll
    for (int j = 0; j < 2; j++) {
        const int col = e0 + wc * 32 + j * 16 + lrow;
        const float w = -__expf(td[col]);
        float s = 0.f;
#pragma unroll
        for (int i = 0; i < 4; i++)
#pragma unroll
            for (int r = 0; r < 4; r++) {
                const int rl = i * 16 + kq * 4 + r;           // 0..63
                s += __expf(w * (float)(63 - rl)) * ak[i][j][r] * av[i][j][r];
            }
        s += __shfl_xor(s, 16);
        s += __shfl_xor(s, 32);
        if (kq == 0) {
            const int gchunk = blockIdx.x * 2 + wr;           // global chunk id
            cs[(size_t)gchunk * DIMD + col] = s;
        }
    }
}

// ---------------------------------------------------------------------------
// Final GEMM: C[n,e] = sum_d A[n,d] * W[e,d], f32 out. (m97 structure)
// ---------------------------------------------------------------------------
__global__ __launch_bounds__(256, 2)
void gemm_bt(const ushort_t* __restrict__ A,
             const ushort_t* __restrict__ W,
             float* __restrict__ Of)
{
    __shared__ __align__(16) ushort_t As[BM * BK];
    __shared__ __align__(16) ushort_t Bs[BN * BK];

    const int tid  = threadIdx.x;
    const int lane = tid & 63;
    const int wv   = tid >> 6;
    const int wr   = wv >> 1;
    const int wc   = wv & 1;
    const int lrow = lane & 15;
    const int kq   = lane >> 4;

    const int row0 = blockIdx.x * BM;
    const int e0   = blockIdx.y * BN;

    f32x4 acc[4][4];
#pragma unroll
    for (int i = 0; i < 4; i++)
#pragma unroll
        for (int j = 0; j < 4; j++)
            acc[i][j] = f32x4{0.f, 0.f, 0.f, 0.f};

    for (int kt = 0; kt < DIMD / BK; ++kt) {
        const int k0 = kt * BK;

        __syncthreads();

#pragma unroll
        for (int it = 0; it < 2; ++it) {
            const int chunk = tid + it * 256;
            const int r = chunk >> 2;
            const int c = (chunk & 3) << 3;
            const ushort_t* ga = A + (size_t)(row0 + r) * DIMD + k0 + c;
            const ushort_t* gb = W + (size_t)(e0 + r) * DIMD + k0 + c;
            __builtin_amdgcn_global_load_lds(
                (__attribute__((address_space(1))) void*)ga,
                (__attribute__((address_space(3))) void*)((char*)As + chunk * 16),
                16, 0, 0);
            __builtin_amdgcn_global_load_lds(
                (__attribute__((address_space(1))) void*)gb,
                (__attribute__((address_space(3))) void*)((char*)Bs + chunk * 16),
                16, 0, 0);
        }

        __syncthreads();

        bf16x8 af[4], bfr[4];
#pragma unroll
        for (int i = 0; i < 4; i++)
            af[i] = *(const bf16x8*)(As + (wr * 64 + i * 16 + lrow) * BK + kq * 8);
#pragma unroll
        for (int j = 0; j < 4; j++)
            bfr[j] = *(const bf16x8*)(Bs + (wc * 64 + j * 16 + lrow) * BK + kq * 8);

#pragma unroll
        for (int i = 0; i < 4; i++)
#pragma unroll
            for (int j = 0; j < 4; j++)
                acc[i][j] = __builtin_amdgcn_mfma_f32_16x16x32_bf16(
                    af[i], bfr[j], acc[i][j], 0, 0, 0);
    }

#pragma unroll
    for (int i = 0; i < 4; i++)
#pragma unroll
        for (int j = 0; j < 4; j++)
#pragma unroll
            for (int r = 0; r < 4; r++) {
                const int row = row0 + wr * 64 + i * 16 + kq * 4 + r;
                const int col = e0 + wc * 64 + j * 16 + lrow;
                Of[(size_t)row * DIMD + col] = acc[i][j][r];
            }
}

// ---------------------------------------------------------------------------
// Emit with fused chunk scan: incoming state st = prefix over raw chunk sums
// (cs is L2-resident, 1 MB), then out_pre = r*(st + eu*kv); st = decay*st+kv.
// 8 d's/thread; loop count c is wave-uniform (wave spans d only).
// ---------------------------------------------------------------------------
__global__ __launch_bounds__(256)
void emit(const ushort_t* __restrict__ kvb, const ushort_t* __restrict__ rb,
          const float* __restrict__ td, const float* __restrict__ tf,
          const float* __restrict__ cs, ushort_t* __restrict__ op)
{
    const int t  = blockIdx.x * 256 + threadIdx.x;   // 32768 threads
    const int d0 = (t & (DIMD / 8 - 1)) * 8;
    const int bc = t >> 7;
    const int c  = bc & (NCHUNK - 1);
    const int b  = bc >> 6;

    float w[8], decay[8], decayL[8], eu[8], st[8];
#pragma unroll
    for (int j = 0; j < 8; j++) {
        w[j]      = -__expf(td[d0 + j]);
        decay[j]  = __expf(w[j]);
        decayL[j] = __expf(w[j] * (float)CHUNK);
        eu[j]     = __expf(tf[d0 + j]);
        st[j]     = 0.f;
    }

    // Inline scan: st = sum_{c'<c} decayL^(c-1-c') * S[c']
    for (int cc = 0; cc < c; ++cc) {
        const float* sp = cs + (((size_t)b * NCHUNK + cc) * DIMD + d0);
        const float4 s0 = *(const float4*)sp;
        const float4 s1 = *(const float4*)(sp + 4);
        st[0] = decayL[0] * st[0] + s0.x;  st[1] = decayL[1] * st[1] + s0.y;
        st[2] = decayL[2] * st[2] + s0.z;  st[3] = decayL[3] * st[3] + s0.w;
        st[4] = decayL[4] * st[4] + s1.x;  st[5] = decayL[5] * st[5] + s1.y;
        st[6] = decayL[6] * st[6] + s1.z;  st[7] = decayL[7] * st[7] + s1.w;
    }

    size_t off = ((size_t)b * SEQ + (size_t)c * CHUNK) * DIMD + d0;
#pragma unroll 8
    for (int i = 0; i < CHUNK; i++) {
        const u16x8 kv8 = *(const u16x8*)(kvb + off);
        const u16x8 r8  = *(const u16x8*)(rb + off);
        u16x8 o8;
#pragma unroll
        for (int j = 0; j < 8; j++) {
            const float kv = b2f(kv8[j]);
            o8[j] = f2b(b2f(r8[j]) * (st[j] + eu[j] * kv));
            st[j] = decay[j] * st[j] + kv;
        }
        *(u16x8*)(op + off) = o8;
        off += DIMD;
    }
}

// ---------------------------------------------------------------------------
// ws: xb/pbuf 32 MiB + weights 8 MiB + cs 1 MiB = 41 MiB.
// d_out (64 MiB f32) doubles as kvb+rb scratch (dead before final GEMM).
// ---------------------------------------------------------------------------
extern "C" void kernel_launch(void* const* d_in, const int* in_sizes, int n_in,
                              void* d_out, int out_size, void* d_ws, size_t ws_size,
                              hipStream_t stream)
{
    const float* x  = (const float*)d_in[0];
    const float* Wk = (const float*)d_in[1];
    const float* Wv = (const float*)d_in[2];
    const float* Wr = (const float*)d_in[3];
    const float* Wo = (const float*)d_in[4];
    const float* td = (const float*)d_in[5];
    const float* tf = (const float*)d_in[6];

    ushort_t* xb  = (ushort_t*)d_ws;                       // 32 MiB; reused as pbuf
    ushort_t* Wb  = xb + (size_t)NTOK * DIMD;              // 8 MiB (4 matrices)
    ushort_t* Wkb = Wb;
    ushort_t* Wvb = Wb + (size_t)DIMD * DIMD;
    ushort_t* Wrb = Wb + 2 * (size_t)DIMD * DIMD;
    ushort_t* Wob = Wb + 3 * (size_t)DIMD * DIMD;
    float*    cs  = (float*)(Wb + 4 * (size_t)DIMD * DIMD); // 1 MiB
    ushort_t* pbuf = xb;

    ushort_t* kvb = (ushort_t*)d_out;                      // 32 MiB scratch
    ushort_t* rb  = kvb + (size_t)NTOK * DIMD;             // 32 MiB scratch
    float*    out = (float*)d_out;

    // 0) all conversions in one dispatch
    conv_all<<<(XU + 4 * WU) / 256, 256, 0, stream>>>(x, Wk, Wv, Wr, Wo, xb, Wb);

    // 1) fused kv & r projections + per-chunk aggregates
    gemm_kvr<<<dim3(NTOK / BMF, DIMD / BNF), 256, 0, stream>>>(
        xb, Wkb, Wvb, Wrb, td, kvb, rb, cs);

    // 2) emit (with inline chunk-boundary scan) -> pbuf (xb region)
    emit<<<BATCH * NCHUNK * (DIMD / 8) / 256, 256, 0, stream>>>(
        kvb, rb, td, tf, cs, pbuf);

    // 3) out = out_pre @ Wo^T (f32 epilogue, overwrites d_out)
    gemm_bt<<<dim3(NTOK / BM, DIMD / BN), 256, 0, stream>>>(pbuf, Wob, out);
}